// Round 2
// 456.700 us; speedup vs baseline: 1.1016x; 1.1016x over previous
//
#include <hip/hip_runtime.h>
#include <math.h>

#define MSG 128
#define KN 32

typedef float vf4 __attribute__((ext_vector_type(4)));

// ---------------------------------------------------------------------------
// Prep: M'[d][e] = (1/sqrt(128)) * sum_a Wk[a][d] * Wq[a][e]
//       c'[d]    = (1/sqrt(128)) * sum_a Wk[a][d] * bq[a]
// Q·bk is constant across neighbors -> cancels in softmax, dropped.
// ---------------------------------------------------------------------------
__global__ void gac_prep(const float* __restrict__ Wq, const float* __restrict__ bq,
                         const float* __restrict__ Wk,
                         float* __restrict__ Mp, float* __restrict__ cp) {
    const float inv_scale = 0.088388347648318440f; // 1/sqrt(128)
    const int d = blockIdx.x;   // 0..127
    const int e = threadIdx.x;  // 0..127
    float acc = 0.f;
#pragma unroll 8
    for (int a = 0; a < 128; ++a)
        acc = fmaf(Wk[a * 128 + d], Wq[a * 128 + e], acc);
    Mp[d * 128 + e] = acc * inv_scale;

    if (threadIdx.x < 64) {  // wave 0 computes c'[d]
        const int l = threadIdx.x;
        float p = Wk[l * 128 + d] * bq[l] + Wk[(l + 64) * 128 + d] * bq[l + 64];
#pragma unroll
        for (int off = 32; off; off >>= 1) p += __shfl_down(p, off, 64);
        if (l == 0) cp[d] = p * inv_scale;
    }
}

// ---------------------------------------------------------------------------
// Fully fused: one block = 16 nodes.
//   P2: q'' = q @ M'^T + c'   (M' rows phase-scoped in regs, h-split)
//   P3: wave-per-node attention+context, barrier-free inside the phase.
//       PAIR LAYOUT: each dwordx4 load i covers rows 2i (lanes 0-31) and
//       2i+1 (lanes 32-63), dims 4*(l&31).. — 16 loads/node (16 B/lane),
//       one 5-step half-wave butterfly yields BOTH scores of the pair.
//   P4: out = ctx @ Wv^T + bv (Wv rows phase-scoped in regs)
// Register lifetimes wA -> xv -> wV are disjoint: peak ~110 VGPR, 4 waves/EU.
// LDS 32 KB. Nontemporal hints on all zero-reuse streams (nbr/query/out).
// ---------------------------------------------------------------------------
__global__ __launch_bounds__(256, 4)
void gac_fused(const float* __restrict__ query,
               const float* __restrict__ nbr,
               const float* __restrict__ Mp,
               const float* __restrict__ cp,
               const float* __restrict__ Wv,
               const float* __restrict__ bv,
               float* __restrict__ out, int N) {
    __shared__ __align__(16) float bufA[16 * 128];      // q, then ctx (8 KB)
    __shared__ __align__(16) float q2[16 * 128];        // q''       (8 KB)
    __shared__ __align__(16) float part[2 * 16 * 128];  // h-partials (16 KB)

    const int t = threadIdx.x;
    const int r = t & 127;   // matvec output row
    const int h = t >> 7;    // inner-dim half
    const int w = t >> 6;    // wave 0..3
    const int l = t & 63;    // lane

    const int n0 = blockIdx.x * 16;
    const size_t maxf4 = (size_t)N * 32 - 1;

    // ---- stage q for 16 nodes (coalesced float4, nontemporal) ----
    {
        const vf4* src = (const vf4*)query;
        size_t i0 = (size_t)n0 * 32 + t;
        size_t i1 = i0 + 256;
        ((vf4*)bufA)[t]       = __builtin_nontemporal_load(src + (i0 > maxf4 ? maxf4 : i0));
        ((vf4*)bufA)[t + 256] = __builtin_nontemporal_load(src + (i1 > maxf4 ? maxf4 : i1));
    }
    __syncthreads();  // B1

    // ---- P2: q'' = M' q + c' ----
    {
        vf4 wA[16];
        const vf4* wp = (const vf4*)(Mp + r * 128 + h * 64);
#pragma unroll
        for (int i = 0; i < 16; ++i) wA[i] = wp[i];
        const float br = (h == 0) ? cp[r] : 0.f;
        float acc[16];
#pragma unroll
        for (int j = 0; j < 16; ++j) acc[j] = br;
#pragma unroll
        for (int i = 0; i < 16; ++i) {
            const vf4 w4 = wA[i];
#pragma unroll
            for (int j = 0; j < 16; ++j) {
                const vf4 q4 = ((const vf4*)(bufA + j * 128 + h * 64))[i]; // LDS broadcast
                acc[j] = fmaf(w4.x, q4.x, acc[j]);
                acc[j] = fmaf(w4.y, q4.y, acc[j]);
                acc[j] = fmaf(w4.z, q4.z, acc[j]);
                acc[j] = fmaf(w4.w, q4.w, acc[j]);
            }
        }
#pragma unroll
        for (int j = 0; j < 16; ++j) part[h * 2048 + j * 128 + r] = acc[j];
    }
    __syncthreads();  // B2
#pragma unroll
    for (int i = 0; i < 2; ++i) {   // vectorized h-combine (b128)
        const int e4 = t + 256 * i;
        const vf4 pa = ((const vf4*)part)[e4];
        const vf4 pb = ((const vf4*)(part + 2048))[e4];
        ((vf4*)q2)[e4] = pa + pb;
    }
    __syncthreads();  // B3

    // ---- P3: attention + context, wave-per-node, 4 nodes per wave ----
#pragma unroll 1     // keep xv footprint to a single node
    for (int jj = 0; jj < 4; ++jj) {
        const int ln = 4 * w + jj;
        int n = n0 + ln;
        if (n >= N) n = N - 1;               // clamped garbage, store guarded later
        const vf4* x4 = (const vf4*)(nbr + (size_t)n * KN * MSG);
        vf4 xv[16];
#pragma unroll
        for (int i = 0; i < 16; ++i)
            xv[i] = __builtin_nontemporal_load(x4 + i * 64 + l);  // rows 2i / 2i+1
        const vf4 qq = ((const vf4*)(q2 + ln * 128))[l & 31];

        // scores: one 5-step half-wave butterfly per PAIR of neighbors.
        // After pair i: lanes 0-31 all hold dot(row 2i, q''), lanes 32-63 row 2i+1.
        // Lane l keeps k = 2*(l&15) + (l>>5)  (each k duplicated at l^16).
        float s = 0.f;
        const int li = l & 15;
#pragma unroll
        for (int i = 0; i < 16; ++i) {
            float p = xv[i].x * qq.x;
            p = fmaf(xv[i].y, qq.y, p);
            p = fmaf(xv[i].z, qq.z, p);
            p = fmaf(xv[i].w, qq.w, p);
            p += __shfl_xor(p, 16, 64);
            p += __shfl_xor(p, 8, 64);
            p += __shfl_xor(p, 4, 64);
            p += __shfl_xor(p, 2, 64);
            p += __shfl_xor(p, 1, 64);
            if (li == i) s = p;
        }
        // softmax over 32 ks: 16 distinct per 16-lane group (+dup at l^16),
        // parity split at l^32. 5 shuffles for max, 5 for sum.
        float m = s;
        m = fmaxf(m, __shfl_xor(m, 8, 64));
        m = fmaxf(m, __shfl_xor(m, 4, 64));
        m = fmaxf(m, __shfl_xor(m, 2, 64));
        m = fmaxf(m, __shfl_xor(m, 1, 64));
        m = fmaxf(m, __shfl_xor(m, 32, 64));
        const float e = __expf(s - m);
        float sum = e;
        sum += __shfl_xor(sum, 8, 64);
        sum += __shfl_xor(sum, 4, 64);
        sum += __shfl_xor(sum, 2, 64);
        sum += __shfl_xor(sum, 1, 64);
        sum += __shfl_xor(sum, 32, 64);
        const float a = e / sum;

        // context: a_{2i} lives at lane i (+16), a_{2i+1} at lane 32+i (+48).
        // Each half accumulates its parity's rows; one xor-32 combine at end.
        float cx = 0.f, cy = 0.f, cz = 0.f, cw = 0.f;
        const int half = l & 32;
#pragma unroll
        for (int i = 0; i < 16; ++i) {
            const float ak = __shfl(a, i + half, 64);
            cx = fmaf(ak, xv[i].x, cx);
            cy = fmaf(ak, xv[i].y, cy);
            cz = fmaf(ak, xv[i].z, cz);
            cw = fmaf(ak, xv[i].w, cw);
        }
        cx += __shfl_xor(cx, 32, 64);
        cy += __shfl_xor(cy, 32, 64);
        cz += __shfl_xor(cz, 32, 64);
        cw += __shfl_xor(cw, 32, 64);
        if (l < 32) {
            vf4 c; c.x = cx; c.y = cy; c.z = cz; c.w = cw;
            ((vf4*)(bufA + ln * 128))[l] = c;  // q is dead; reuse bufA
        }
    }
    __syncthreads();  // B4

    // ---- P4: out = Wv ctx + bv ----
    {
        vf4 wV[16];
        const vf4* wp = (const vf4*)(Wv + r * 128 + h * 64);
#pragma unroll
        for (int i = 0; i < 16; ++i) wV[i] = wp[i];
        const float br = (h == 0) ? bv[r] : 0.f;
        float acc[16];
#pragma unroll
        for (int j = 0; j < 16; ++j) acc[j] = br;
#pragma unroll
        for (int i = 0; i < 16; ++i) {
            const vf4 w4 = wV[i];
#pragma unroll
            for (int j = 0; j < 16; ++j) {
                const vf4 c4 = ((const vf4*)(bufA + j * 128 + h * 64))[i];
                acc[j] = fmaf(w4.x, c4.x, acc[j]);
                acc[j] = fmaf(w4.y, c4.y, acc[j]);
                acc[j] = fmaf(w4.z, c4.z, acc[j]);
                acc[j] = fmaf(w4.w, c4.w, acc[j]);
            }
        }
#pragma unroll
        for (int j = 0; j < 16; ++j) part[h * 2048 + j * 128 + r] = acc[j];
    }
    __syncthreads();  // B5
#pragma unroll
    for (int i = 0; i < 2; ++i) {   // vectorized h-combine + dwordx4 NT store
        const int e4 = t + 256 * i;
        const vf4 pa = ((const vf4*)part)[e4];
        const vf4 pb = ((const vf4*)(part + 2048))[e4];
        const vf4 v = pa + pb;
        const size_t idx4 = (size_t)n0 * 32 + e4;
        if (idx4 < (size_t)N * 32)
            __builtin_nontemporal_store(v, (vf4*)out + idx4);
    }
}

extern "C" void kernel_launch(void* const* d_in, const int* in_sizes, int n_in,
                              void* d_out, int out_size, void* d_ws, size_t ws_size,
                              hipStream_t stream) {
    const float* query = (const float*)d_in[0];
    const float* nbr   = (const float*)d_in[1];
    const float* Wq    = (const float*)d_in[2];
    const float* bq    = (const float*)d_in[3];
    const float* Wk    = (const float*)d_in[4];
    /* bk = d_in[5] unused: Q·bk is constant across k -> softmax-invariant */
    const float* Wv    = (const float*)d_in[6];
    const float* bv    = (const float*)d_in[7];
    float* out = (float*)d_out;

    const int N = in_sizes[0] / MSG;

    float* Mp = (float*)d_ws;       // 128*128
    float* cp = Mp + 128 * 128;     // 128

    gac_prep<<<128, 128, 0, stream>>>(Wq, bq, Wk, Mp, cp);

    const int grid = (N + 15) / 16;  // 1250
    gac_fused<<<grid, 256, 0, stream>>>(query, nbr, Mp, cp, Wv, bv, out, N);
}